// Round 2
// baseline (2166.664 us; speedup 1.0000x reference)
//
#include <hip/hip_runtime.h>

typedef unsigned short u16;
typedef unsigned int u32;
typedef float f32x4 __attribute__((ext_vector_type(4)));
typedef short bf16x8 __attribute__((ext_vector_type(8)));   // 8 bf16 bit-patterns (4 VGPRs)

#define DEV static __device__ __forceinline__

DEV float bf2f(u16 u){ union{float f; u32 i;} x; x.i = ((u32)u) << 16; return x.f; }
DEV u16 f2bf(float f){ union{float f; u32 i;} x; x.f = f; u32 u = x.i;
  return (u16)((u + 0x7fffu + ((u >> 16) & 1u)) >> 16); }           // RNE
DEV uint4 pack8(const u16* s){ uint4 v;
  v.x = (u32)s[0] | ((u32)s[1]<<16); v.y = (u32)s[2] | ((u32)s[3]<<16);
  v.z = (u32)s[4] | ((u32)s[5]<<16); v.w = (u32)s[6] | ((u32)s[7]<<16); return v; }
DEV f32x4 mfma16(bf16x8 a, bf16x8 b, f32x4 c){
  return __builtin_amdgcn_mfma_f32_16x16x32_bf16(a, b, c, 0, 0, 0);
}
DEV bf16x8 ldfrag(const u16* p){ return *(const bf16x8*)p; }

constexpr float SCL = 144.269504088896341f;    // 100*log2(e) = 1/(eps*ln2), eps=0.01
constexpr float LOG2MU = -9.99998522680257f;   // log2(1/1024 + 1e-8)

// ---------------- workspace layout ----------------
constexpr size_t MB = 1ull << 20;
constexpr size_t OFF_G    = 0;                 // fp32 [4][1024][1024]  G = (dot-1)*SCL
constexpr size_t OFF_GT   = 16*MB;             // fp32 transpose of G
constexpr size_t OFF_U    = 32*MB;             // fp32 [4][1024]
constexpr size_t OFF_V    = OFF_U   + (16<<10);
constexpr size_t OFF_INC  = OFF_V   + (16<<10);// inv pixel norms content [4096]
constexpr size_t OFF_INS  = OFF_INC + (16<<10);
constexpr size_t OFF_CNM  = OFF_INS + (16<<10);// content chan mean [4][512]
constexpr size_t OFF_CNIS = OFF_CNM + (8<<10); // content chan 1/std
constexpr size_t OFF_BNS  = OFF_CNIS+ (8<<10); // BN sums: [layer][sum|sumsq][256] = 4 KB
constexpr size_t OFF_SCLS = OFF_BNS + (4<<10); // scale1,shift1,scale2,shift2 (4*256 f32)
constexpr size_t OFF_CNT  = OFF_SCLS+ (4<<10); // grid-barrier counter
constexpr size_t OFF_CFH  = 33*MB;             // bf16 [4][1024][512] normalized content hi
constexpr size_t OFF_CFL  = OFF_CFH + 4*MB;
constexpr size_t OFF_SFH  = OFF_CFL + 4*MB;
constexpr size_t OFF_SFL  = OFF_SFH + 4*MB;
constexpr size_t OFF_SNB  = OFF_SFL + 4*MB;    // bf16 style NCHW [4][512][1024]
constexpr size_t OFF_TN   = OFF_SNB + 4*MB;    // fp32 t NHWC [4][1024][512]
constexpr size_t OFF_TC   = OFF_TN  + 8*MB;    // bf16 concat NHWC [4][1024][1024]
constexpr size_t OFF_W1P  = OFF_TC  + 8*MB;    // bf16 [9][256][1024]
constexpr size_t OFF_W2P  = OFF_W1P + 9*256*1024*2;
constexpr size_t OFF_W3P  = OFF_W2P + 9*256*256*2;
constexpr size_t OFF_WDP  = OFF_W3P + 9*512*256*2;   // [9][16][512] (co padded to 16)
// reuse of CFH..SFL (dead after cgemm) for conv activations:
constexpr size_t OFF_Z1 = OFF_CFH;             // fp32 [4][1024][256] relu(conv1)
constexpr size_t OFF_A1 = OFF_CFH + 4*MB;      // bf16 [4][1024][256]
constexpr size_t OFF_Z2 = OFF_CFH + 6*MB;
constexpr size_t OFF_A2 = OFF_CFH + 10*MB;
constexpr size_t OFF_T2 = OFF_CFH + 12*MB;     // bf16 [4][1024][512] alpha*cn + t

// ---------------- prep kernels ----------------
__global__ void pack_w_k(const float* __restrict__ w, u16* __restrict__ wp, int CO, int CI){
  int idx = blockIdx.x*256 + threadIdx.x;
  if (idx >= CO*CI*9) return;
  int ci = idx % CI; int r = idx / CI; int co = r % CO; int tap = r / CO;
  wp[idx] = f2bf(w[(size_t)(co*CI + ci)*9 + tap]);
}

__global__ void pack_wdec_k(const float* __restrict__ w, u16* __restrict__ wp){
  int idx = blockIdx.x*256 + threadIdx.x;      // 9*16*512
  if (idx >= 9*16*512) return;
  int ci = idx & 511; int r = idx >> 9; int co = r & 15; int tap = r >> 4;
  wp[idx] = f2bf((co < 3) ? w[(size_t)(co*512 + ci)*9 + tap] : 0.f);
}

__global__ void pix_norms_k(const float* __restrict__ cf, const float* __restrict__ sf,
                            float* __restrict__ inc, float* __restrict__ ins){
  int p = blockIdx.x*256 + threadIdx.x;        // 0..4095
  const float* src = blockIdx.y ? sf : cf;
  float* dst = blockIdx.y ? ins : inc;
  int b = p >> 10, pp = p & 1023;
  const float* base = src + (size_t)b*512*1024 + pp;
  float s = 0.f;
  #pragma unroll 8
  for (int d = 0; d < 512; ++d){ float x = base[(size_t)d*1024]; s += x*x; }
  dst[p] = rsqrtf(s);
}

__global__ void chan_stats_k(const float* __restrict__ cf, float* __restrict__ cnm,
                             float* __restrict__ cnis){
  int bd = blockIdx.x;                          // 0..2047 = b*512+d
  float4 v = ((const float4*)(cf + (size_t)bd*1024))[threadIdx.x];
  float s = v.x+v.y+v.z+v.w;
  float q = v.x*v.x+v.y*v.y+v.z*v.z+v.w*v.w;
  #pragma unroll
  for (int m = 32; m >= 1; m >>= 1){ s += __shfl_xor(s, m, 64); q += __shfl_xor(q, m, 64); }
  __shared__ float ls[4], lq[4];
  int w = threadIdx.x >> 6;
  if ((threadIdx.x & 63) == 0){ ls[w] = s; lq[w] = q; }
  __syncthreads();
  if (threadIdx.x == 0){
    float S = ls[0]+ls[1]+ls[2]+ls[3], Q = lq[0]+lq[1]+lq[2]+lq[3];
    float mean = S * (1.f/1024.f);
    float var  = Q * (1.f/1024.f) - mean*mean;
    cnm[bd] = mean; cnis[bd] = rsqrtf(var + 1e-5f);
  }
}

// NCHW fp32 -> points-layout [p][d]: normalized bf16 hi/lo split (+aux copies)
__global__ void tsplit_k(const float* __restrict__ src, const float* __restrict__ invn,
                         u16* __restrict__ hi, u16* __restrict__ lo,
                         u16* __restrict__ aux, int is_style){
  __shared__ float tile[64][65];
  int b = blockIdx.z, p0 = blockIdx.x*64, d0 = blockIdx.y*64;
  int r = threadIdx.x >> 2, c0 = (threadIdx.x & 3) * 16;
  const float* sp = src + ((size_t)(b*512 + d0 + r))*1024 + p0 + c0;
  float v[16];
  #pragma unroll
  for (int e = 0; e < 4; ++e){
    float4 t4 = ((const float4*)sp)[e];
    v[e*4+0]=t4.x; v[e*4+1]=t4.y; v[e*4+2]=t4.z; v[e*4+3]=t4.w;
  }
  #pragma unroll
  for (int j = 0; j < 16; ++j) tile[r][c0+j] = v[j];
  if (is_style){                               // style NCHW bf16 (t-GEMM B operand)
    u16 t16[16];
    #pragma unroll
    for (int j = 0; j < 16; ++j) t16[j] = f2bf(v[j]);
    uint4* ap = (uint4*)(aux + ((size_t)(b*512 + d0 + r))*1024 + p0 + c0);
    ap[0] = pack8(t16); ap[1] = pack8(t16+8);
  }
  __syncthreads();
  int pr = r, dc0 = c0;
  float inv = invn[(b<<10) + p0 + pr];
  u16 h16[16], l16[16], t16[16];
  #pragma unroll
  for (int j = 0; j < 16; ++j){
    float x = tile[dc0+j][pr];
    t16[j] = f2bf(x);
    float xn = x * inv;
    u16 h = f2bf(xn);
    h16[j] = h;
    l16[j] = f2bf(xn - bf2f(h));
  }
  size_t orow = (size_t)((b<<10) + p0 + pr);
  uint4* hp = (uint4*)(hi + orow*512 + d0 + dc0);
  uint4* lp = (uint4*)(lo + orow*512 + d0 + dc0);
  hp[0] = pack8(h16); hp[1] = pack8(h16+8);
  lp[0] = pack8(l16); lp[1] = pack8(l16+8);
  if (!is_style){                              // raw content -> concat[:,512:] bf16
    uint4* ap = (uint4*)(aux + orow*1024 + 512 + d0 + dc0);
    ap[0] = pack8(t16); ap[1] = pack8(t16+8);
  }
}

// ---------------- C-GEMM: G = (cfn . sfn - 1)*SCL, fp32-grade via bf16 hi/lo split
__global__ __launch_bounds__(256) void cgemm_k(const u16* __restrict__ cfh, const u16* __restrict__ cfl,
        const u16* __restrict__ sfh, const u16* __restrict__ sfl,
        float* __restrict__ G, float* __restrict__ Gt){
  __shared__ __align__(16) u16 Ah[128*32], Al[128*32], Bh[128*32], Bl[128*32];
  int b = blockIdx.z;
  size_t abase = ((size_t)((b<<10) + blockIdx.x*128))*512;
  size_t bbase = ((size_t)((b<<10) + blockIdx.y*128))*512;
  int lane = threadIdx.x & 63, wid = threadIdx.x >> 6;
  int wm = (wid >> 1)*64, wn = (wid & 1)*64;
  int fr = lane & 15, qd = lane >> 4;
  int sr = threadIdx.x >> 1, sc = (threadIdx.x & 1)*16;
  f32x4 acc[4][4] = {};
  for (int kk = 0; kk < 512; kk += 32){
    size_t g0 = (size_t)sr*512 + kk + sc;
    *(uint4*)&Ah[sr*32+sc]   = *(const uint4*)(cfh + abase + g0);
    *(uint4*)&Ah[sr*32+sc+8] = *(const uint4*)(cfh + abase + g0 + 8);
    *(uint4*)&Al[sr*32+sc]   = *(const uint4*)(cfl + abase + g0);
    *(uint4*)&Al[sr*32+sc+8] = *(const uint4*)(cfl + abase + g0 + 8);
    *(uint4*)&Bh[sr*32+sc]   = *(const uint4*)(sfh + bbase + g0);
    *(uint4*)&Bh[sr*32+sc+8] = *(const uint4*)(sfh + bbase + g0 + 8);
    *(uint4*)&Bl[sr*32+sc]   = *(const uint4*)(sfl + bbase + g0);
    *(uint4*)&Bl[sr*32+sc+8] = *(const uint4*)(sfl + bbase + g0 + 8);
    __syncthreads();
    bf16x8 bhf[4], blf[4];
    #pragma unroll
    for (int ni = 0; ni < 4; ++ni){
      bhf[ni] = ldfrag(&Bh[(wn + ni*16 + fr)*32 + qd*8]);
      blf[ni] = ldfrag(&Bl[(wn + ni*16 + fr)*32 + qd*8]);
    }
    #pragma unroll
    for (int mi = 0; mi < 4; ++mi){
      bf16x8 ah = ldfrag(&Ah[(wm + mi*16 + fr)*32 + qd*8]);
      bf16x8 al = ldfrag(&Al[(wm + mi*16 + fr)*32 + qd*8]);
      #pragma unroll
      for (int ni = 0; ni < 4; ++ni){
        acc[mi][ni] = mfma16(ah, bhf[ni], acc[mi][ni]);
        acc[mi][ni] = mfma16(ah, blf[ni], acc[mi][ni]);
        acc[mi][ni] = mfma16(al, bhf[ni], acc[mi][ni]);
      }
    }
    __syncthreads();
  }
  size_t gb = ((size_t)b) << 20;
  #pragma unroll
  for (int mi = 0; mi < 4; ++mi)
    #pragma unroll
    for (int ni = 0; ni < 4; ++ni)
      #pragma unroll
      for (int rg = 0; rg < 4; ++rg){
        int ig = blockIdx.x*128 + wm + mi*16 + qd*4 + rg;
        int jg = blockIdx.y*128 + wn + ni*16 + fr;
        float g = (acc[mi][ni][rg] - 1.f) * SCL;
        G [gb + (size_t)ig*1024 + jg] = g;
        Gt[gb + (size_t)jg*1024 + ig] = g;
      }
}

// ---------------- persistent Sinkhorn: 20 iterations, device-scope grid barrier
DEV void grid_barrier(int* cnt, int target){
  __syncthreads();
  __threadfence();                              // release prior writes device-wide
  if (threadIdx.x == 0){
    __hip_atomic_fetch_add(cnt, 1, __ATOMIC_RELAXED, __HIP_MEMORY_SCOPE_AGENT);
    while (__hip_atomic_load(cnt, __ATOMIC_RELAXED, __HIP_MEMORY_SCOPE_AGENT) < target)
      __builtin_amdgcn_s_sleep(2);
  }
  __syncthreads();
  __threadfence();                              // acquire before reading others' data
}

DEV void lse_row(const float* __restrict__ Mrow, const float* __restrict__ addv,
                 float* __restrict__ outp, int lane){
  const float4* r4 = (const float4*)Mrow;
  const float4* a4 = (const float4*)addv;
  float x[16]; float mx = -3.0e38f;
  #pragma unroll
  for (int e = 0; e < 4; ++e){
    float4 g = r4[lane + 64*e]; float4 a = a4[lane + 64*e];
    x[e*4+0] = g.x + a.x; x[e*4+1] = g.y + a.y; x[e*4+2] = g.z + a.z; x[e*4+3] = g.w + a.w;
    mx = fmaxf(mx, fmaxf(fmaxf(x[e*4+0], x[e*4+1]), fmaxf(x[e*4+2], x[e*4+3])));
  }
  #pragma unroll
  for (int m = 32; m >= 1; m >>= 1) mx = fmaxf(mx, __shfl_xor(mx, m, 64));
  float s = 0.f;
  #pragma unroll
  for (int i = 0; i < 16; ++i) s += exp2f(x[i] - mx);
  #pragma unroll
  for (int m = 32; m >= 1; m >>= 1) s += __shfl_xor(s, m, 64);
  if (lane == 0) *outp = LOG2MU - (mx + log2f(s));
}

__global__ __launch_bounds__(256) void sinkhorn_k(const float* __restrict__ G,
        const float* __restrict__ Gt, float* __restrict__ U, float* __restrict__ V,
        int* cnt){
  int wid = threadIdx.x >> 6, lane = threadIdx.x & 63;
  int row0 = blockIdx.x*16 + wid*4;             // 256 blocks x 16 rows = 4096 rows
  int phase = 0;
  for (int it = 0; it < 20; ++it){
    #pragma unroll
    for (int i = 0; i < 4; ++i){
      int row = row0 + i, b = row >> 10;
      lse_row(G + ((size_t)row << 10), V + ((size_t)b << 10), U + row, lane);
    }
    ++phase; grid_barrier(cnt, phase*256);
    #pragma unroll
    for (int i = 0; i < 4; ++i){
      int row = row0 + i, b = row >> 10;
      lse_row(Gt + ((size_t)row << 10), U + ((size_t)b << 10), V + row, lane);
    }
    if (it != 19){ ++phase; grid_barrier(cnt, phase*256); }
  }
}

// ---------------- t = pi @ sf (pi = 2^(G+U+V+10) generated in staging)
__global__ __launch_bounds__(256) void tgemm_k(const float* __restrict__ G, const float* __restrict__ U,
        const float* __restrict__ V, const u16* __restrict__ snb,
        float* __restrict__ tn, u16* __restrict__ tc){
  __shared__ __align__(16) u16 As[128*32], Bs[128*32];
  int b = blockIdx.z, p0 = blockIdx.x*128, d0 = blockIdx.y*128;
  const float* Gb = G + (((size_t)b) << 20);
  const float* Vb = V + (b << 10);
  int lane = threadIdx.x & 63, wid = threadIdx.x >> 6;
  int wm = (wid >> 1)*64, wn = (wid & 1)*64;
  int fr = lane & 15, qd = lane >> 4;
  int sr = threadIdx.x >> 1, sc = (threadIdx.x & 1)*16;
  float u_r = U[(b<<10) + p0 + sr] + 10.f;     // +10: fold pi * 1024
  const u16* Brow = snb + ((size_t)(b*512 + d0 + sr))*1024;
  f32x4 acc[4][4] = {};
  for (int kk = 0; kk < 1024; kk += 32){
    const float4* g4 = (const float4*)(Gb + (size_t)(p0 + sr)*1024 + kk + sc);
    const float4* v4 = (const float4*)(Vb + kk + sc);
    u16 t16[16];
    #pragma unroll
    for (int e = 0; e < 4; ++e){
      float4 g = g4[e]; float4 vv = v4[e];
      t16[e*4+0] = f2bf(exp2f(g.x + vv.x + u_r));
      t16[e*4+1] = f2bf(exp2f(g.y + vv.y + u_r));
      t16[e*4+2] = f2bf(exp2f(g.z + vv.z + u_r));
      t16[e*4+3] = f2bf(exp2f(g.w + vv.w + u_r));
    }
    *(uint4*)&As[sr*32 + sc]     = pack8(t16);
    *(uint4*)&As[sr*32 + sc + 8] = pack8(t16 + 8);
    *(uint4*)&Bs[sr*32 + sc]     = *(const uint4*)(Brow + kk + sc);
    *(uint4*)&Bs[sr*32 + sc + 8] = *(const uint4*)(Brow + kk + sc + 8);
    __syncthreads();
    bf16x8 bfr[4];
    #pragma unroll
    for (int ni = 0; ni < 4; ++ni) bfr[ni] = ldfrag(&Bs[(wn + ni*16 + fr)*32 + qd*8]);
    #pragma unroll
    for (int mi = 0; mi < 4; ++mi){
      bf16x8 afr = ldfrag(&As[(wm + mi*16 + fr)*32 + qd*8]);
      #pragma unroll
      for (int ni = 0; ni < 4; ++ni) acc[mi][ni] = mfma16(afr, bfr[ni], acc[mi][ni]);
    }
    __syncthreads();
  }
  #pragma unroll
  for (int mi = 0; mi < 4; ++mi)
    #pragma unroll
    for (int ni = 0; ni < 4; ++ni)
      #pragma unroll
      for (int rg = 0; rg < 4; ++rg){
        int p = p0 + wm + mi*16 + qd*4 + rg;
        int d = d0 + wn + ni*16 + fr;
        float vout = acc[mi][ni][rg];
        size_t ro = (size_t)((b<<10) + p);
        tn[ro*512 + d] = vout;
        tc[ro*1024 + d] = f2bf(vout);          // concat[:, :512] = t
      }
}

// ---------------- implicit-GEMM 3x3 conv, NHWC activations, [tap][co][ci] weights
// MODE 0: relu(conv+bias) -> fp32 NHWC   MODE 1: alpha-combine -> bf16 t2
template<int CI, int CO, int MW, int NW, int WM, int WN, int MODE>
__global__ __launch_bounds__(256) void conv_k(const u16* __restrict__ in, const u16* __restrict__ wp,
        const float* __restrict__ bias, float* __restrict__ fout, u16* __restrict__ bout,
        const u16* __restrict__ tc, const float* __restrict__ cnm, const float* __restrict__ cnis,
        const float* __restrict__ tn){
  constexpr int MT = MW*WM*16, NT = NW*WN*16;
  __shared__ __align__(16) u16 As[MT*32], Bs[NT*32];
  int b = blockIdx.z, p0 = blockIdx.x*MT, c0 = blockIdx.y*NT;
  int lane = threadIdx.x & 63, wid = threadIdx.x >> 6;
  int wm = (wid / NW) * (WM*16), wn = (wid % NW) * (WN*16);
  int fr = lane & 15, qd = lane >> 4;
  int ar = threadIdx.x >> 2, ac = (threadIdx.x & 3) * 8;   // MT==64: 256 threads stage exactly
  int p = p0 + ar, py = p >> 5, px = p & 31;
  f32x4 acc[WM][WN] = {};
  for (int tap = 0; tap < 9; ++tap){
    int dy = tap/3 - 1, dx = tap%3 - 1;
    int sy = py + dy, sx = px + dx;
    bool ok = ((unsigned)sy < 32u) && ((unsigned)sx < 32u);
    size_t arow = ((size_t)((b<<10) + (sy<<5) + sx)) * CI;
    size_t wrow = ((size_t)(tap*CO + c0 + ar)) * CI;
    for (int ck = 0; ck < CI; ck += 32){
      uint4 av = {0,0,0,0};
      if (ok) av = *(const uint4*)(in + arow + ck + ac);
      *(uint4*)&As[ar*32 + ac] = av;
      if (threadIdx.x < NT*4)
        *(uint4*)&Bs[ar*32 + ac] = *(const uint4*)(wp + wrow + ck + ac);
      __syncthreads();
      bf16x8 bfr[WN];
      #pragma unroll
      for (int ni = 0; ni < WN; ++ni) bfr[ni] = ldfrag(&Bs[(wn + ni*16 + fr)*32 + qd*8]);
      #pragma unroll
      for (int mi = 0; mi < WM; ++mi){
        bf16x8 afr = ldfrag(&As[(wm + mi*16 + fr)*32 + qd*8]);
        #pragma unroll
        for (int ni = 0; ni < WN; ++ni) acc[mi][ni] = mfma16(afr, bfr[ni], acc[mi][ni]);
      }
      __syncthreads();
    }
  }
  #pragma unroll
  for (int mi = 0; mi < WM; ++mi)
    #pragma unroll
    for (int ni = 0; ni < WN; ++ni)
      #pragma unroll
      for (int rg = 0; rg < 4; ++rg){
        int pp = p0 + wm + mi*16 + qd*4 + rg;
        int cc = c0 + wn + ni*16 + fr;
        float v = acc[mi][ni][rg];
        size_t ro = (size_t)((b<<10) + pp);
        if (MODE == 0){
          v += bias[cc]; v = fmaxf(v, 0.f);
          fout[ro*CO + cc] = v;
        } else {
          float alpha = v + bias[cc];
          float cn = (bf2f(tc[ro*1024 + 512 + cc]) - cnm[(b<<9) + cc]) * cnis[(b<<9) + cc];
          bout[ro*512 + cc] = f2bf(alpha*cn + tn[ro*512 + cc]);
        }
      }
}

// ---------------- decoder conv (512 -> 3): VALU reduction, 16 threads per pixel
__global__ __launch_bounds__(256) void dec_k(const u16* __restrict__ t2, const u16* __restrict__ wdp,
                                             const float* __restrict__ db, float* __restrict__ out){
  __shared__ float wlds[3*4608];                // [c][tap][ci] fp32, 55.3 KB
  int tid = threadIdx.x;
  for (int k = tid; k < 3*4608; k += 256){
    int c = k / 4608, rem = k - c*4608;
    int tap = rem >> 9, ci = rem & 511;
    wlds[k] = bf2f(wdp[(size_t)(tap*16 + c)*512 + ci]);
  }
  __syncthreads();
  int b = blockIdx.x >> 6;
  int p = ((blockIdx.x & 63) << 4) + (tid >> 4); // pixel within batch image
  int sub = tid & 15;
  int py = p >> 5, px = p & 31;
  float a0 = 0.f, a1 = 0.f, a2 = 0.f;
  for (int tap = 0; tap < 9; ++tap){
    int sy = py + tap/3 - 1, sx = px + tap%3 - 1;
    if (((unsigned)sy < 32u) && ((unsigned)sx < 32u)){
      const u16* srow = t2 + ((size_t)((b<<10) + (sy<<5) + sx))*512;
      const float* w0 = wlds + tap*512;
      #pragma unroll
      for (int j = 0; j < 4; ++j){
        int ci = j*128 + sub*8;
        uint4 v = *(const uint4*)(srow + ci);
        u32 ww[4] = {v.x, v.y, v.z, v.w};
        #pragma unroll
        for (int e = 0; e < 8; ++e){
          float x = bf2f((u16)((e & 1) ? (ww[e>>1] >> 16) : (ww[e>>1] & 0xffffu)));
          a0 += x * w0[ci + e];
          a1 += x * w0[4608 + ci + e];
          a2 += x * w0[9216 + ci + e];
        }
      }
    }
  }
  #pragma unroll
  for (int m = 8; m >= 1; m >>= 1){
    a0 += __shfl_xor(a0, m, 64);
    a1 += __shfl_xor(a1, m, 64);
    a2 += __shfl_xor(a2, m, 64);
  }
  if (sub == 0){
    out[((size_t)(b*3 + 0) << 10) + p] = a0 + db[0];
    out[((size_t)(b*3 + 1) << 10) + p] = a1 + db[1];
    out[((size_t)(b*3 + 2) << 10) + p] = a2 + db[2];
  }
}

// ---------------- BN (training-mode batch stats) ----------------
__global__ void bn_stats_k(const float* __restrict__ z, float* __restrict__ sums, int C){
  int c = blockIdx.x*64 + (threadIdx.x & 63);
  int w = threadIdx.x >> 6;
  int rbase = blockIdx.y*512 + w*128;
  float s = 0.f, q = 0.f;
  for (int i = 0; i < 128; ++i){
    float x = z[(size_t)(rbase + i)*C + c];
    s += x; q += x*x;
  }
  __shared__ float ls[4][64], lq[4][64];
  ls[w][threadIdx.x & 63] = s; lq[w][threadIdx.x & 63] = q;
  __syncthreads();
  if (threadIdx.x < 64){
    float S = ls[0][threadIdx.x]+ls[1][threadIdx.x]+ls[2][threadIdx.x]+ls[3][threadIdx.x];
    float Q = lq[0][threadIdx.x]+lq[1][threadIdx.x]+lq[2][threadIdx.x]+lq[3][threadIdx.x];
    atomicAdd(&sums[blockIdx.x*64 + threadIdx.x], S);
    atomicAdd(&sums[C + blockIdx.x*64 + threadIdx.x], Q);
  }
}

__global__ void bn_fin_k(const float* __restrict__ sums, const float* __restrict__ gamma,
                         const float* __restrict__ beta, float* __restrict__ scale,
                         float* __restrict__ shift, int C){
  int c = blockIdx.x*256 + threadIdx.x;
  if (c >= C) return;
  float mean = sums[c] * (1.f/4096.f);
  float var  = sums[C + c] * (1.f/4096.f) - mean*mean;
  float sc = gamma[c] * rsqrtf(var + 1e-5f);
  scale[c] = sc; shift[c] = beta[c] - mean*sc;
}

__global__ void bn_apply_k(const float* __restrict__ z, const float* __restrict__ scale,
                           const float* __restrict__ shift, u16* __restrict__ a, int C){
  int idx = blockIdx.x*256 + threadIdx.x;
  float4 v = ((const float4*)z)[idx];
  int c0 = (idx*4) & (C-1);
  u16 o[4];
  o[0] = f2bf(v.x*scale[c0+0] + shift[c0+0]);
  o[1] = f2bf(v.y*scale[c0+1] + shift[c0+1]);
  o[2] = f2bf(v.z*scale[c0+2] + shift[c0+2]);
  o[3] = f2bf(v.w*scale[c0+3] + shift[c0+3]);
  uint2 pk; pk.x = (u32)o[0] | ((u32)o[1]<<16); pk.y = (u32)o[2] | ((u32)o[3]<<16);
  ((uint2*)a)[idx] = pk;
}

// ---------------- launch ----------------
extern "C" void kernel_launch(void* const* d_in, const int* in_sizes, int n_in,
                              void* d_out, int out_size, void* d_ws, size_t ws_size,
                              hipStream_t stream){
  const float* cf  = (const float*)d_in[0];
  const float* sf  = (const float*)d_in[1];
  const float* w1  = (const float*)d_in[2];
  const float* b1  = (const float*)d_in[3];
  const float* g1  = (const float*)d_in[4];
  const float* be1 = (const float*)d_in[5];
  const float* w2  = (const float*)d_in[6];
  const float* b2  = (const float*)d_in[7];
  const float* g2  = (const float*)d_in[8];
  const float* be2 = (const float*)d_in[9];
  const float* w3  = (const float*)d_in[10];
  const float* b3  = (const float*)d_in[11];
  const float* dw  = (const float*)d_in[12];
  const float* db  = (const float*)d_in[13];

  char* ws = (char*)d_ws;
  float* G    = (float*)(ws + OFF_G);
  float* Gt   = (float*)(ws + OFF_GT);
  float* U    = (float*)(ws + OFF_U);
  float* V    = (float*)(ws + OFF_V);
  float* inc  = (float*)(ws + OFF_INC);
  float* ins  = (float*)(ws + OFF_INS);
  float* cnm  = (float*)(ws + OFF_CNM);
  float* cnis = (float*)(ws + OFF_CNIS);
  float* bns1 = (float*)(ws + OFF_BNS);
  float* bns2 = bns1 + 512;
  float* scl1 = (float*)(ws + OFF_SCLS);
  float* sft1 = scl1 + 256;
  float* scl2 = sft1 + 256;
  float* sft2 = scl2 + 256;
  int*   cnt  = (int*)(ws + OFF_CNT);
  u16* cfh = (u16*)(ws + OFF_CFH);
  u16* cfl = (u16*)(ws + OFF_CFL);
  u16* sfh = (u16*)(ws + OFF_SFH);
  u16* sfl = (u16*)(ws + OFF_SFL);
  u16* snb = (u16*)(ws + OFF_SNB);
  float* tn  = (float*)(ws + OFF_TN);
  u16* tc  = (u16*)(ws + OFF_TC);
  u16* w1p = (u16*)(ws + OFF_W1P);
  u16* w2p = (u16*)(ws + OFF_W2P);
  u16* w3p = (u16*)(ws + OFF_W3P);
  u16* wdp = (u16*)(ws + OFF_WDP);
  float* z1 = (float*)(ws + OFF_Z1);
  u16*   a1 = (u16*)(ws + OFF_A1);
  float* z2 = (float*)(ws + OFF_Z2);
  u16*   a2 = (u16*)(ws + OFF_A2);
  u16*   t2 = (u16*)(ws + OFF_T2);

  hipMemsetAsync(ws + OFF_U, 0, 32 << 10, stream);    // U and V
  hipMemsetAsync(ws + OFF_BNS, 0, 12 << 10, stream);  // BN sums + scales + barrier cnt

  pack_w_k<<<(256*1024*9 + 255)/256, 256, 0, stream>>>(w1, w1p, 256, 1024);
  pack_w_k<<<(256*256*9 + 255)/256, 256, 0, stream>>>(w2, w2p, 256, 256);
  pack_w_k<<<(512*256*9 + 255)/256, 256, 0, stream>>>(w3, w3p, 512, 256);
  pack_wdec_k<<<(9*16*512 + 255)/256, 256, 0, stream>>>(dw, wdp);

  pix_norms_k<<<dim3(16, 2), 256, 0, stream>>>(cf, sf, inc, ins);
  chan_stats_k<<<2048, 256, 0, stream>>>(cf, cnm, cnis);
  tsplit_k<<<dim3(16, 8, 4), 256, 0, stream>>>(cf, inc, cfh, cfl, tc, 0);
  tsplit_k<<<dim3(16, 8, 4), 256, 0, stream>>>(sf, ins, sfh, sfl, snb, 1);

  cgemm_k<<<dim3(8, 8, 4), 256, 0, stream>>>(cfh, cfl, sfh, sfl, G, Gt);

  sinkhorn_k<<<256, 256, 0, stream>>>(G, Gt, U, V, cnt);

  tgemm_k<<<dim3(8, 4, 4), 256, 0, stream>>>(G, U, V, snb, tn, tc);

  conv_k<1024, 256, 2, 2, 2, 2, 0><<<dim3(16, 4, 4), 256, 0, stream>>>(
      tc, w1p, b1, z1, nullptr, nullptr, nullptr, nullptr, nullptr);
  bn_stats_k<<<dim3(4, 8), 256, 0, stream>>>(z1, bns1, 256);
  bn_fin_k<<<1, 256, 0, stream>>>(bns1, g1, be1, scl1, sft1, 256);
  bn_apply_k<<<1024, 256, 0, stream>>>(z1, scl1, sft1, a1, 256);

  conv_k<256, 256, 2, 2, 2, 2, 0><<<dim3(16, 4, 4), 256, 0, stream>>>(
      a1, w2p, b2, z2, nullptr, nullptr, nullptr, nullptr, nullptr);
  bn_stats_k<<<dim3(4, 8), 256, 0, stream>>>(z2, bns2, 256);
  bn_fin_k<<<1, 256, 0, stream>>>(bns2, g2, be2, scl2, sft2, 256);
  bn_apply_k<<<1024, 256, 0, stream>>>(z2, scl2, sft2, a2, 256);

  conv_k<256, 512, 2, 2, 2, 2, 1><<<dim3(16, 8, 4), 256, 0, stream>>>(
      a2, w3p, b3, nullptr, t2, tc, cnm, cnis, tn);

  dec_k<<<256, 256, 0, stream>>>(t2, wdp, db, (float*)d_out);

  (void)in_sizes; (void)n_in; (void)out_size; (void)ws_size;
}

// Round 3
// 649.039 us; speedup vs baseline: 3.3383x; 3.3383x over previous
//
#include <hip/hip_runtime.h>

typedef unsigned short u16;
typedef unsigned int u32;
typedef float f32x4 __attribute__((ext_vector_type(4)));
typedef short bf16x8 __attribute__((ext_vector_type(8)));   // 8 bf16 bit-patterns (4 VGPRs)

#define DEV static __device__ __forceinline__

DEV float bf2f(u16 u){ union{float f; u32 i;} x; x.i = ((u32)u) << 16; return x.f; }
DEV u16 f2bf(float f){ union{float f; u32 i;} x; x.f = f; u32 u = x.i;
  return (u16)((u + 0x7fffu + ((u >> 16) & 1u)) >> 16); }           // RNE
DEV uint4 pack8(const u16* s){ uint4 v;
  v.x = (u32)s[0] | ((u32)s[1]<<16); v.y = (u32)s[2] | ((u32)s[3]<<16);
  v.z = (u32)s[4] | ((u32)s[5]<<16); v.w = (u32)s[6] | ((u32)s[7]<<16); return v; }
DEV f32x4 mfma16(bf16x8 a, bf16x8 b, f32x4 c){
  return __builtin_amdgcn_mfma_f32_16x16x32_bf16(a, b, c, 0, 0, 0);
}
DEV bf16x8 ldfrag(const u16* p){ return *(const bf16x8*)p; }

constexpr float SCL = 144.269504088896341f;    // 100*log2(e) = 1/(eps*ln2), eps=0.01
constexpr float LOG2MU = -9.99998522680257f;   // log2(1/1024 + 1e-8)

// ---------------- workspace layout ----------------
constexpr size_t MB = 1ull << 20;
constexpr size_t OFF_G    = 0;                 // fp32 [4][1024][1024]  G = (dot-1)*SCL
constexpr size_t OFF_GT   = 16*MB;             // fp32 transpose of G
constexpr size_t OFF_U    = 32*MB;             // fp32 [4][1024]
constexpr size_t OFF_V    = OFF_U   + (16<<10);
constexpr size_t OFF_INC  = OFF_V   + (16<<10);// inv pixel norms content [4096]
constexpr size_t OFF_INS  = OFF_INC + (16<<10);
constexpr size_t OFF_CNM  = OFF_INS + (16<<10);// content chan mean [4][512]
constexpr size_t OFF_CNIS = OFF_CNM + (8<<10); // content chan 1/std
constexpr size_t OFF_BNS  = OFF_CNIS+ (8<<10); // BN sums: [layer][sum|sumsq][256] = 4 KB
constexpr size_t OFF_SCLS = OFF_BNS + (4<<10); // scale1,shift1,scale2,shift2 (4*256 f32)
constexpr size_t OFF_CFH  = 33*MB;             // bf16 [4][1024][512] normalized content hi
constexpr size_t OFF_CFL  = OFF_CFH + 4*MB;
constexpr size_t OFF_SFH  = OFF_CFL + 4*MB;
constexpr size_t OFF_SFL  = OFF_SFH + 4*MB;
constexpr size_t OFF_SNB  = OFF_SFL + 4*MB;    // bf16 style NCHW [4][512][1024]
constexpr size_t OFF_TN   = OFF_SNB + 4*MB;    // fp32 t NHWC [4][1024][512]
constexpr size_t OFF_TC   = OFF_TN  + 8*MB;    // bf16 concat NHWC [4][1024][1024]
constexpr size_t OFF_W1P  = OFF_TC  + 8*MB;    // bf16 [9][256][1024]
constexpr size_t OFF_W2P  = OFF_W1P + 9*256*1024*2;
constexpr size_t OFF_W3P  = OFF_W2P + 9*256*256*2;
constexpr size_t OFF_WDP  = OFF_W3P + 9*512*256*2;   // [9][16][512] (co padded to 16)
// reuse of CFH..SFL (dead after cgemm) for conv activations:
constexpr size_t OFF_Z1 = OFF_CFH;             // fp32 [4][1024][256] relu(conv1)
constexpr size_t OFF_A1 = OFF_CFH + 4*MB;      // bf16 [4][1024][256]
constexpr size_t OFF_Z2 = OFF_CFH + 6*MB;
constexpr size_t OFF_A2 = OFF_CFH + 10*MB;
constexpr size_t OFF_T2 = OFF_CFH + 12*MB;     // bf16 [4][1024][512] alpha*cn + t

// ---------------- prep kernels ----------------
__global__ void pack_w_k(const float* __restrict__ w, u16* __restrict__ wp, int CO, int CI){
  int idx = blockIdx.x*256 + threadIdx.x;
  if (idx >= CO*CI*9) return;
  int ci = idx % CI; int r = idx / CI; int co = r % CO; int tap = r / CO;
  wp[idx] = f2bf(w[(size_t)(co*CI + ci)*9 + tap]);
}

__global__ void pack_wdec_k(const float* __restrict__ w, u16* __restrict__ wp){
  int idx = blockIdx.x*256 + threadIdx.x;      // 9*16*512
  if (idx >= 9*16*512) return;
  int ci = idx & 511; int r = idx >> 9; int co = r & 15; int tap = r >> 4;
  wp[idx] = f2bf((co < 3) ? w[(size_t)(co*512 + ci)*9 + tap] : 0.f);
}

__global__ void pix_norms_k(const float* __restrict__ cf, const float* __restrict__ sf,
                            float* __restrict__ inc, float* __restrict__ ins){
  int p = blockIdx.x*256 + threadIdx.x;        // 0..4095
  const float* src = blockIdx.y ? sf : cf;
  float* dst = blockIdx.y ? ins : inc;
  int b = p >> 10, pp = p & 1023;
  const float* base = src + (size_t)b*512*1024 + pp;
  float s = 0.f;
  #pragma unroll 8
  for (int d = 0; d < 512; ++d){ float x = base[(size_t)d*1024]; s += x*x; }
  dst[p] = rsqrtf(s);
}

__global__ void chan_stats_k(const float* __restrict__ cf, float* __restrict__ cnm,
                             float* __restrict__ cnis){
  int bd = blockIdx.x;                          // 0..2047 = b*512+d
  float4 v = ((const float4*)(cf + (size_t)bd*1024))[threadIdx.x];
  float s = v.x+v.y+v.z+v.w;
  float q = v.x*v.x+v.y*v.y+v.z*v.z+v.w*v.w;
  #pragma unroll
  for (int m = 32; m >= 1; m >>= 1){ s += __shfl_xor(s, m, 64); q += __shfl_xor(q, m, 64); }
  __shared__ float ls[4], lq[4];
  int w = threadIdx.x >> 6;
  if ((threadIdx.x & 63) == 0){ ls[w] = s; lq[w] = q; }
  __syncthreads();
  if (threadIdx.x == 0){
    float S = ls[0]+ls[1]+ls[2]+ls[3], Q = lq[0]+lq[1]+lq[2]+lq[3];
    float mean = S * (1.f/1024.f);
    float var  = Q * (1.f/1024.f) - mean*mean;
    cnm[bd] = mean; cnis[bd] = rsqrtf(var + 1e-5f);
  }
}

// NCHW fp32 -> points-layout [p][d]: normalized bf16 hi/lo split (+aux copies)
__global__ void tsplit_k(const float* __restrict__ src, const float* __restrict__ invn,
                         u16* __restrict__ hi, u16* __restrict__ lo,
                         u16* __restrict__ aux, int is_style){
  __shared__ float tile[64][65];
  int b = blockIdx.z, p0 = blockIdx.x*64, d0 = blockIdx.y*64;
  int r = threadIdx.x >> 2, c0 = (threadIdx.x & 3) * 16;
  const float* sp = src + ((size_t)(b*512 + d0 + r))*1024 + p0 + c0;
  float v[16];
  #pragma unroll
  for (int e = 0; e < 4; ++e){
    float4 t4 = ((const float4*)sp)[e];
    v[e*4+0]=t4.x; v[e*4+1]=t4.y; v[e*4+2]=t4.z; v[e*4+3]=t4.w;
  }
  #pragma unroll
  for (int j = 0; j < 16; ++j) tile[r][c0+j] = v[j];
  if (is_style){                               // style NCHW bf16 (t-GEMM B operand)
    u16 t16[16];
    #pragma unroll
    for (int j = 0; j < 16; ++j) t16[j] = f2bf(v[j]);
    uint4* ap = (uint4*)(aux + ((size_t)(b*512 + d0 + r))*1024 + p0 + c0);
    ap[0] = pack8(t16); ap[1] = pack8(t16+8);
  }
  __syncthreads();
  int pr = r, dc0 = c0;
  float inv = invn[(b<<10) + p0 + pr];
  u16 h16[16], l16[16], t16[16];
  #pragma unroll
  for (int j = 0; j < 16; ++j){
    float x = tile[dc0+j][pr];
    t16[j] = f2bf(x);
    float xn = x * inv;
    u16 h = f2bf(xn);
    h16[j] = h;
    l16[j] = f2bf(xn - bf2f(h));
  }
  size_t orow = (size_t)((b<<10) + p0 + pr);
  uint4* hp = (uint4*)(hi + orow*512 + d0 + dc0);
  uint4* lp = (uint4*)(lo + orow*512 + d0 + dc0);
  hp[0] = pack8(h16); hp[1] = pack8(h16+8);
  lp[0] = pack8(l16); lp[1] = pack8(l16+8);
  if (!is_style){                              // raw content -> concat[:,512:] bf16
    uint4* ap = (uint4*)(aux + orow*1024 + 512 + d0 + dc0);
    ap[0] = pack8(t16); ap[1] = pack8(t16+8);
  }
}

// ---------------- C-GEMM: G = (cfn . sfn - 1)*SCL, fp32-grade via bf16 hi/lo split
__global__ __launch_bounds__(256) void cgemm_k(const u16* __restrict__ cfh, const u16* __restrict__ cfl,
        const u16* __restrict__ sfh, const u16* __restrict__ sfl,
        float* __restrict__ G, float* __restrict__ Gt){
  __shared__ __align__(16) u16 Ah[128*32], Al[128*32], Bh[128*32], Bl[128*32];
  int b = blockIdx.z;
  size_t abase = ((size_t)((b<<10) + blockIdx.x*128))*512;
  size_t bbase = ((size_t)((b<<10) + blockIdx.y*128))*512;
  int lane = threadIdx.x & 63, wid = threadIdx.x >> 6;
  int wm = (wid >> 1)*64, wn = (wid & 1)*64;
  int fr = lane & 15, qd = lane >> 4;
  int sr = threadIdx.x >> 1, sc = (threadIdx.x & 1)*16;
  f32x4 acc[4][4] = {};
  for (int kk = 0; kk < 512; kk += 32){
    size_t g0 = (size_t)sr*512 + kk + sc;
    *(uint4*)&Ah[sr*32+sc]   = *(const uint4*)(cfh + abase + g0);
    *(uint4*)&Ah[sr*32+sc+8] = *(const uint4*)(cfh + abase + g0 + 8);
    *(uint4*)&Al[sr*32+sc]   = *(const uint4*)(cfl + abase + g0);
    *(uint4*)&Al[sr*32+sc+8] = *(const uint4*)(cfl + abase + g0 + 8);
    *(uint4*)&Bh[sr*32+sc]   = *(const uint4*)(sfh + bbase + g0);
    *(uint4*)&Bh[sr*32+sc+8] = *(const uint4*)(sfh + bbase + g0 + 8);
    *(uint4*)&Bl[sr*32+sc]   = *(const uint4*)(sfl + bbase + g0);
    *(uint4*)&Bl[sr*32+sc+8] = *(const uint4*)(sfl + bbase + g0 + 8);
    __syncthreads();
    bf16x8 bhf[4], blf[4];
    #pragma unroll
    for (int ni = 0; ni < 4; ++ni){
      bhf[ni] = ldfrag(&Bh[(wn + ni*16 + fr)*32 + qd*8]);
      blf[ni] = ldfrag(&Bl[(wn + ni*16 + fr)*32 + qd*8]);
    }
    #pragma unroll
    for (int mi = 0; mi < 4; ++mi){
      bf16x8 ah = ldfrag(&Ah[(wm + mi*16 + fr)*32 + qd*8]);
      bf16x8 al = ldfrag(&Al[(wm + mi*16 + fr)*32 + qd*8]);
      #pragma unroll
      for (int ni = 0; ni < 4; ++ni){
        acc[mi][ni] = mfma16(ah, bhf[ni], acc[mi][ni]);
        acc[mi][ni] = mfma16(ah, blf[ni], acc[mi][ni]);
        acc[mi][ni] = mfma16(al, bhf[ni], acc[mi][ni]);
      }
    }
    __syncthreads();
  }
  size_t gb = ((size_t)b) << 20;
  #pragma unroll
  for (int mi = 0; mi < 4; ++mi)
    #pragma unroll
    for (int ni = 0; ni < 4; ++ni)
      #pragma unroll
      for (int rg = 0; rg < 4; ++rg){
        int ig = blockIdx.x*128 + wm + mi*16 + qd*4 + rg;
        int jg = blockIdx.y*128 + wn + ni*16 + fr;
        float g = (acc[mi][ni][rg] - 1.f) * SCL;
        G [gb + (size_t)ig*1024 + jg] = g;
        Gt[gb + (size_t)jg*1024 + ig] = g;
      }
}

// ---------------- Sinkhorn log2-domain pass: out[r] = LOG2MU - log2 sum_j 2^(M[r][j]+addv[j])
__global__ void lse_k(const float* __restrict__ M, const float* __restrict__ addv,
                      float* __restrict__ outv, float log2mass){
  int row = blockIdx.x*4 + (threadIdx.x >> 6);
  int lane = threadIdx.x & 63;
  int b = row >> 10;
  const float4* r4 = (const float4*)(M + ((size_t)row << 10));
  const float4* a4 = (const float4*)(addv + ((size_t)b << 10));
  float x[16]; float mx = -3.0e38f;
  #pragma unroll
  for (int e = 0; e < 4; ++e){
    float4 g = r4[lane + 64*e]; float4 a = a4[lane + 64*e];
    x[e*4+0] = g.x + a.x; x[e*4+1] = g.y + a.y; x[e*4+2] = g.z + a.z; x[e*4+3] = g.w + a.w;
    mx = fmaxf(mx, fmaxf(fmaxf(x[e*4+0], x[e*4+1]), fmaxf(x[e*4+2], x[e*4+3])));
  }
  #pragma unroll
  for (int m = 32; m >= 1; m >>= 1) mx = fmaxf(mx, __shfl_xor(mx, m, 64));
  float s = 0.f;
  #pragma unroll
  for (int i = 0; i < 16; ++i) s += exp2f(x[i] - mx);
  #pragma unroll
  for (int m = 32; m >= 1; m >>= 1) s += __shfl_xor(s, m, 64);
  if (lane == 0) outv[row] = log2mass - (mx + log2f(s));
}

// ---------------- t = pi @ sf (pi = 2^(G+U+V+10) generated in staging)
__global__ __launch_bounds__(256) void tgemm_k(const float* __restrict__ G, const float* __restrict__ U,
        const float* __restrict__ V, const u16* __restrict__ snb,
        float* __restrict__ tn, u16* __restrict__ tc){
  __shared__ __align__(16) u16 As[128*32], Bs[128*32];
  int b = blockIdx.z, p0 = blockIdx.x*128, d0 = blockIdx.y*128;
  const float* Gb = G + (((size_t)b) << 20);
  const float* Vb = V + (b << 10);
  int lane = threadIdx.x & 63, wid = threadIdx.x >> 6;
  int wm = (wid >> 1)*64, wn = (wid & 1)*64;
  int fr = lane & 15, qd = lane >> 4;
  int sr = threadIdx.x >> 1, sc = (threadIdx.x & 1)*16;
  float u_r = U[(b<<10) + p0 + sr] + 10.f;     // +10: fold pi * 1024
  const u16* Brow = snb + ((size_t)(b*512 + d0 + sr))*1024;
  f32x4 acc[4][4] = {};
  for (int kk = 0; kk < 1024; kk += 32){
    const float4* g4 = (const float4*)(Gb + (size_t)(p0 + sr)*1024 + kk + sc);
    const float4* v4 = (const float4*)(Vb + kk + sc);
    u16 t16[16];
    #pragma unroll
    for (int e = 0; e < 4; ++e){
      float4 g = g4[e]; float4 vv = v4[e];
      t16[e*4+0] = f2bf(exp2f(g.x + vv.x + u_r));
      t16[e*4+1] = f2bf(exp2f(g.y + vv.y + u_r));
      t16[e*4+2] = f2bf(exp2f(g.z + vv.z + u_r));
      t16[e*4+3] = f2bf(exp2f(g.w + vv.w + u_r));
    }
    *(uint4*)&As[sr*32 + sc]     = pack8(t16);
    *(uint4*)&As[sr*32 + sc + 8] = pack8(t16 + 8);
    *(uint4*)&Bs[sr*32 + sc]     = *(const uint4*)(Brow + kk + sc);
    *(uint4*)&Bs[sr*32 + sc + 8] = *(const uint4*)(Brow + kk + sc + 8);
    __syncthreads();
    bf16x8 bfr[4];
    #pragma unroll
    for (int ni = 0; ni < 4; ++ni) bfr[ni] = ldfrag(&Bs[(wn + ni*16 + fr)*32 + qd*8]);
    #pragma unroll
    for (int mi = 0; mi < 4; ++mi){
      bf16x8 afr = ldfrag(&As[(wm + mi*16 + fr)*32 + qd*8]);
      #pragma unroll
      for (int ni = 0; ni < 4; ++ni) acc[mi][ni] = mfma16(afr, bfr[ni], acc[mi][ni]);
    }
    __syncthreads();
  }
  #pragma unroll
  for (int mi = 0; mi < 4; ++mi)
    #pragma unroll
    for (int ni = 0; ni < 4; ++ni)
      #pragma unroll
      for (int rg = 0; rg < 4; ++rg){
        int p = p0 + wm + mi*16 + qd*4 + rg;
        int d = d0 + wn + ni*16 + fr;
        float vout = acc[mi][ni][rg];
        size_t ro = (size_t)((b<<10) + p);
        tn[ro*512 + d] = vout;
        tc[ro*1024 + d] = f2bf(vout);          // concat[:, :512] = t
      }
}

// ---------------- implicit-GEMM 3x3 conv, NHWC activations, [tap][co][ci] weights
// MODE 0: relu(conv+bias) -> fp32 NHWC   MODE 1: alpha-combine -> bf16 t2
template<int CI, int CO, int MW, int NW, int WM, int WN, int MODE>
__global__ __launch_bounds__(256) void conv_k(const u16* __restrict__ in, const u16* __restrict__ wp,
        const float* __restrict__ bias, float* __restrict__ fout, u16* __restrict__ bout,
        const u16* __restrict__ tc, const float* __restrict__ cnm, const float* __restrict__ cnis,
        const float* __restrict__ tn){
  constexpr int MT = MW*WM*16, NT = NW*WN*16;
  __shared__ __align__(16) u16 As[MT*32], Bs[NT*32];
  int b = blockIdx.z, p0 = blockIdx.x*MT, c0 = blockIdx.y*NT;
  int lane = threadIdx.x & 63, wid = threadIdx.x >> 6;
  int wm = (wid / NW) * (WM*16), wn = (wid % NW) * (WN*16);
  int fr = lane & 15, qd = lane >> 4;
  int ar = threadIdx.x >> 2, ac = (threadIdx.x & 3) * 8;   // MT==64: 256 threads stage exactly
  int p = p0 + ar, py = p >> 5, px = p & 31;
  f32x4 acc[WM][WN] = {};
  for (int tap = 0; tap < 9; ++tap){
    int dy = tap/3 - 1, dx = tap%3 - 1;
    int sy = py + dy, sx = px + dx;
    bool ok = ((unsigned)sy < 32u) && ((unsigned)sx < 32u);
    size_t arow = ((size_t)((b<<10) + (sy<<5) + sx)) * CI;
    size_t wrow = ((size_t)(tap*CO + c0 + ar)) * CI;
    for (int ck = 0; ck < CI; ck += 32){
      uint4 av = {0,0,0,0};
      if (ok) av = *(const uint4*)(in + arow + ck + ac);
      *(uint4*)&As[ar*32 + ac] = av;
      if (threadIdx.x < NT*4)
        *(uint4*)&Bs[ar*32 + ac] = *(const uint4*)(wp + wrow + ck + ac);
      __syncthreads();
      bf16x8 bfr[WN];
      #pragma unroll
      for (int ni = 0; ni < WN; ++ni) bfr[ni] = ldfrag(&Bs[(wn + ni*16 + fr)*32 + qd*8]);
      #pragma unroll
      for (int mi = 0; mi < WM; ++mi){
        bf16x8 afr = ldfrag(&As[(wm + mi*16 + fr)*32 + qd*8]);
        #pragma unroll
        for (int ni = 0; ni < WN; ++ni) acc[mi][ni] = mfma16(afr, bfr[ni], acc[mi][ni]);
      }
      __syncthreads();
    }
  }
  #pragma unroll
  for (int mi = 0; mi < WM; ++mi)
    #pragma unroll
    for (int ni = 0; ni < WN; ++ni)
      #pragma unroll
      for (int rg = 0; rg < 4; ++rg){
        int pp = p0 + wm + mi*16 + qd*4 + rg;
        int cc = c0 + wn + ni*16 + fr;
        float v = acc[mi][ni][rg];
        size_t ro = (size_t)((b<<10) + pp);
        if (MODE == 0){
          v += bias[cc]; v = fmaxf(v, 0.f);
          fout[ro*CO + cc] = v;
        } else {
          float alpha = v + bias[cc];
          float cn = (bf2f(tc[ro*1024 + 512 + cc]) - cnm[(b<<9) + cc]) * cnis[(b<<9) + cc];
          bout[ro*512 + cc] = f2bf(alpha*cn + tn[ro*512 + cc]);
        }
      }
}

// ---------------- decoder conv (512 -> 3): VALU reduction, 16 threads per pixel
__global__ __launch_bounds__(256) void dec_k(const u16* __restrict__ t2, const u16* __restrict__ wdp,
                                             const float* __restrict__ db, float* __restrict__ out){
  __shared__ float wlds[3*4608];                // [c][tap][ci] fp32, 55.3 KB
  int tid = threadIdx.x;
  for (int k = tid; k < 3*4608; k += 256){
    int c = k / 4608, rem = k - c*4608;
    int tap = rem >> 9, ci = rem & 511;
    wlds[k] = bf2f(wdp[(size_t)(tap*16 + c)*512 + ci]);
  }
  __syncthreads();
  int b = blockIdx.x >> 6;
  int p = ((blockIdx.x & 63) << 4) + (tid >> 4); // pixel within batch image
  int sub = tid & 15;
  int py = p >> 5, px = p & 31;
  float a0 = 0.f, a1 = 0.f, a2 = 0.f;
  for (int tap = 0; tap < 9; ++tap){
    int sy = py + tap/3 - 1, sx = px + tap%3 - 1;
    if (((unsigned)sy < 32u) && ((unsigned)sx < 32u)){
      const u16* srow = t2 + ((size_t)((b<<10) + (sy<<5) + sx))*512;
      const float* w0 = wlds + tap*512;
      #pragma unroll
      for (int j = 0; j < 4; ++j){
        int ci = j*128 + sub*8;
        uint4 v = *(const uint4*)(srow + ci);
        u32 ww[4] = {v.x, v.y, v.z, v.w};
        #pragma unroll
        for (int e = 0; e < 8; ++e){
          float x = bf2f((u16)((e & 1) ? (ww[e>>1] >> 16) : (ww[e>>1] & 0xffffu)));
          a0 += x * w0[ci + e];
          a1 += x * w0[4608 + ci + e];
          a2 += x * w0[9216 + ci + e];
        }
      }
    }
  }
  #pragma unroll
  for (int m = 8; m >= 1; m >>= 1){
    a0 += __shfl_xor(a0, m, 64);
    a1 += __shfl_xor(a1, m, 64);
    a2 += __shfl_xor(a2, m, 64);
  }
  if (sub == 0){
    out[((size_t)(b*3 + 0) << 10) + p] = a0 + db[0];
    out[((size_t)(b*3 + 1) << 10) + p] = a1 + db[1];
    out[((size_t)(b*3 + 2) << 10) + p] = a2 + db[2];
  }
}

// ---------------- BN (training-mode batch stats) ----------------
__global__ void bn_stats_k(const float* __restrict__ z, float* __restrict__ sums, int C){
  int c = blockIdx.x*64 + (threadIdx.x & 63);
  int w = threadIdx.x >> 6;
  int rbase = blockIdx.y*512 + w*128;
  float s = 0.f, q = 0.f;
  for (int i = 0; i < 128; ++i){
    float x = z[(size_t)(rbase + i)*C + c];
    s += x; q += x*x;
  }
  __shared__ float ls[4][64], lq[4][64];
  ls[w][threadIdx.x & 63] = s; lq[w][threadIdx.x & 63] = q;
  __syncthreads();
  if (threadIdx.x < 64){
    float S = ls[0][threadIdx.x]+ls[1][threadIdx.x]+ls[2][threadIdx.x]+ls[3][threadIdx.x];
    float Q = lq[0][threadIdx.x]+lq[1][threadIdx.x]+lq[2][threadIdx.x]+lq[3][threadIdx.x];
    atomicAdd(&sums[blockIdx.x*64 + threadIdx.x], S);
    atomicAdd(&sums[C + blockIdx.x*64 + threadIdx.x], Q);
  }
}

__global__ void bn_fin_k(const float* __restrict__ sums, const float* __restrict__ gamma,
                         const float* __restrict__ beta, float* __restrict__ scale,
                         float* __restrict__ shift, int C){
  int c = blockIdx.x*256 + threadIdx.x;
  if (c >= C) return;
  float mean = sums[c] * (1.f/4096.f);
  float var  = sums[C + c] * (1.f/4096.f) - mean*mean;
  float sc = gamma[c] * rsqrtf(var + 1e-5f);
  scale[c] = sc; shift[c] = beta[c] - mean*sc;
}

__global__ void bn_apply_k(const float* __restrict__ z, const float* __restrict__ scale,
                           const float* __restrict__ shift, u16* __restrict__ a, int C){
  int idx = blockIdx.x*256 + threadIdx.x;
  float4 v = ((const float4*)z)[idx];
  int c0 = (idx*4) & (C-1);
  u16 o[4];
  o[0] = f2bf(v.x*scale[c0+0] + shift[c0+0]);
  o[1] = f2bf(v.y*scale[c0+1] + shift[c0+1]);
  o[2] = f2bf(v.z*scale[c0+2] + shift[c0+2]);
  o[3] = f2bf(v.w*scale[c0+3] + shift[c0+3]);
  uint2 pk; pk.x = (u32)o[0] | ((u32)o[1]<<16); pk.y = (u32)o[2] | ((u32)o[3]<<16);
  ((uint2*)a)[idx] = pk;
}

// ---------------- launch ----------------
extern "C" void kernel_launch(void* const* d_in, const int* in_sizes, int n_in,
                              void* d_out, int out_size, void* d_ws, size_t ws_size,
                              hipStream_t stream){
  const float* cf  = (const float*)d_in[0];
  const float* sf  = (const float*)d_in[1];
  const float* w1  = (const float*)d_in[2];
  const float* b1  = (const float*)d_in[3];
  const float* g1  = (const float*)d_in[4];
  const float* be1 = (const float*)d_in[5];
  const float* w2  = (const float*)d_in[6];
  const float* b2  = (const float*)d_in[7];
  const float* g2  = (const float*)d_in[8];
  const float* be2 = (const float*)d_in[9];
  const float* w3  = (const float*)d_in[10];
  const float* b3  = (const float*)d_in[11];
  const float* dw  = (const float*)d_in[12];
  const float* db  = (const float*)d_in[13];

  char* ws = (char*)d_ws;
  float* G    = (float*)(ws + OFF_G);
  float* Gt   = (float*)(ws + OFF_GT);
  float* U    = (float*)(ws + OFF_U);
  float* V    = (float*)(ws + OFF_V);
  float* inc  = (float*)(ws + OFF_INC);
  float* ins  = (float*)(ws + OFF_INS);
  float* cnm  = (float*)(ws + OFF_CNM);
  float* cnis = (float*)(ws + OFF_CNIS);
  float* bns1 = (float*)(ws + OFF_BNS);
  float* bns2 = bns1 + 512;
  float* scl1 = (float*)(ws + OFF_SCLS);
  float* sft1 = scl1 + 256;
  float* scl2 = sft1 + 256;
  float* sft2 = scl2 + 256;
  u16* cfh = (u16*)(ws + OFF_CFH);
  u16* cfl = (u16*)(ws + OFF_CFL);
  u16* sfh = (u16*)(ws + OFF_SFH);
  u16* sfl = (u16*)(ws + OFF_SFL);
  u16* snb = (u16*)(ws + OFF_SNB);
  float* tn  = (float*)(ws + OFF_TN);
  u16* tc  = (u16*)(ws + OFF_TC);
  u16* w1p = (u16*)(ws + OFF_W1P);
  u16* w2p = (u16*)(ws + OFF_W2P);
  u16* w3p = (u16*)(ws + OFF_W3P);
  u16* wdp = (u16*)(ws + OFF_WDP);
  float* z1 = (float*)(ws + OFF_Z1);
  u16*   a1 = (u16*)(ws + OFF_A1);
  float* z2 = (float*)(ws + OFF_Z2);
  u16*   a2 = (u16*)(ws + OFF_A2);
  u16*   t2 = (u16*)(ws + OFF_T2);

  hipMemsetAsync(ws + OFF_U, 0, 32 << 10, stream);    // U and V
  hipMemsetAsync(ws + OFF_BNS, 0, 8 << 10, stream);   // BN sums + scales

  pack_w_k<<<(256*1024*9 + 255)/256, 256, 0, stream>>>(w1, w1p, 256, 1024);
  pack_w_k<<<(256*256*9 + 255)/256, 256, 0, stream>>>(w2, w2p, 256, 256);
  pack_w_k<<<(512*256*9 + 255)/256, 256, 0, stream>>>(w3, w3p, 512, 256);
  pack_wdec_k<<<(9*16*512 + 255)/256, 256, 0, stream>>>(dw, wdp);

  pix_norms_k<<<dim3(16, 2), 256, 0, stream>>>(cf, sf, inc, ins);
  chan_stats_k<<<2048, 256, 0, stream>>>(cf, cnm, cnis);
  tsplit_k<<<dim3(16, 8, 4), 256, 0, stream>>>(cf, inc, cfh, cfl, tc, 0);
  tsplit_k<<<dim3(16, 8, 4), 256, 0, stream>>>(sf, ins, sfh, sfl, snb, 1);

  cgemm_k<<<dim3(8, 8, 4), 256, 0, stream>>>(cfh, cfl, sfh, sfl, G, Gt);

  for (int it = 0; it < 20; ++it){
    lse_k<<<1024, 256, 0, stream>>>(G,  V, U, LOG2MU);
    lse_k<<<1024, 256, 0, stream>>>(Gt, U, V, LOG2MU);
  }

  tgemm_k<<<dim3(8, 4, 4), 256, 0, stream>>>(G, U, V, snb, tn, tc);

  conv_k<1024, 256, 2, 2, 2, 2, 0><<<dim3(16, 4, 4), 256, 0, stream>>>(
      tc, w1p, b1, z1, nullptr, nullptr, nullptr, nullptr, nullptr);
  bn_stats_k<<<dim3(4, 8), 256, 0, stream>>>(z1, bns1, 256);
  bn_fin_k<<<1, 256, 0, stream>>>(bns1, g1, be1, scl1, sft1, 256);
  bn_apply_k<<<1024, 256, 0, stream>>>(z1, scl1, sft1, a1, 256);

  conv_k<256, 256, 2, 2, 2, 2, 0><<<dim3(16, 4, 4), 256, 0, stream>>>(
      a1, w2p, b2, z2, nullptr, nullptr, nullptr, nullptr, nullptr);
  bn_stats_k<<<dim3(4, 8), 256, 0, stream>>>(z2, bns2, 256);
  bn_fin_k<<<1, 256, 0, stream>>>(bns2, g2, be2, scl2, sft2, 256);
  bn_apply_k<<<1024, 256, 0, stream>>>(z2, scl2, sft2, a2, 256);

  conv_k<256, 512, 2, 2, 2, 2, 1><<<dim3(16, 8, 4), 256, 0, stream>>>(
      a2, w3p, b3, nullptr, t2, tc, cnm, cnis, tn);

  dec_k<<<256, 256, 0, stream>>>(t2, wdp, db, (float*)d_out);

  (void)in_sizes; (void)n_in; (void)out_size; (void)ws_size;
}